// Round 1
// baseline (673.663 us; speedup 1.0000x reference)
//
#include <hip/hip_runtime.h>

#define N_NODES 100000
#define N_EDGES 3200000
#define ROWS_PAD 100032   // multiple of 64 for GEMM tiling
#define N_BUCKETS 782     // ceil(100000/128)
#define BUCKET_SHIFT 7

typedef __attribute__((ext_vector_type(8))) short bf16x8;
typedef __attribute__((ext_vector_type(4))) float f32x4;
typedef __attribute__((ext_vector_type(2))) float f32x2;

__device__ __forceinline__ unsigned short f2bf(float f) {
    unsigned u = __float_as_uint(f);
    unsigned r = (u + 0x7fffu + ((u >> 16) & 1u)) >> 16;  // round-to-nearest-even
    return (unsigned short)r;
}
__device__ __forceinline__ float bflo(unsigned u) { return __uint_as_float(u << 16); }
__device__ __forceinline__ float bfhi(unsigned u) { return __uint_as_float(u & 0xffff0000u); }

// ---- convert x fp32 -> fp8 e4m3 [ROWS_PAD,128], 2 elems/thread, zero pad rows ----
__global__ void k_convert_x(const float* __restrict__ x, unsigned short* __restrict__ xf8) {
    int i = blockIdx.x * 256 + threadIdx.x;          // pair index; grid covers ROWS_PAD*64
    int r = i >> 6;
    float2 f = make_float2(0.f, 0.f);
    if (r < N_NODES) f = *(const float2*)(x + 2 * i);
    int pk = __builtin_amdgcn_cvt_pk_fp8_f32(f.x, f.y, 0, false);
    xf8[i] = (unsigned short)(pk & 0xffff);
}

// ---- convert+transpose W [4][k][c] fp32 -> WT [4][c][k] bf16 ----
__global__ void k_convert_w(const float* __restrict__ w, unsigned short* __restrict__ wt) {
    int i = blockIdx.x * 256 + threadIdx.x;          // 65536 total
    int m = i >> 14, rem = i & 16383, k = rem >> 7, c = rem & 127;
    wt[(m << 14) + (c << 7) + k] = f2bf(w[i]);
}

// ---- coarse bucket histogram (row>>7), LDS-aggregated ----
__global__ void __launch_bounds__(256) k_bhist(const int* __restrict__ ei, int* __restrict__ bcnt) {
    __shared__ int h[N_BUCKETS];
    for (int i = threadIdx.x; i < N_BUCKETS; i += 256) h[i] = 0;
    __syncthreads();
    int base = blockIdx.x * 8192;
#pragma unroll
    for (int i = 0; i < 32; ++i) {
        int e = base + threadIdx.x + i * 256;
        if (e < N_EDGES) atomicAdd(&h[ei[e] >> BUCKET_SHIFT], 1);
    }
    __syncthreads();
    for (int i = threadIdx.x; i < N_BUCKETS; i += 256)
        if (h[i]) atomicAdd(&bcnt[i], h[i]);
}

// ---- one-block exclusive scan of bucket counts; also zero ep's 16 pad slots past E ----
__global__ void __launch_bounds__(1024) k_bscan(const int* __restrict__ bcnt,
                                                int* __restrict__ bbase,
                                                int* __restrict__ bcursor,
                                                int* __restrict__ rowstart,
                                                int2* __restrict__ ep) {
    __shared__ int s[1024];
    int t = threadIdx.x;
    int v = (t < N_BUCKETS) ? bcnt[t] : 0;
    s[t] = v;
    __syncthreads();
    for (int off = 1; off < 1024; off <<= 1) {
        int tv = (t >= off) ? s[t - off] : 0;
        __syncthreads();
        s[t] += tv;
        __syncthreads();
    }
    if (t < N_BUCKETS) {
        int ex = s[t] - v;
        bbase[t] = ex;
        bcursor[t] = ex;
    }
    if (t == 0) {
        bbase[N_BUCKETS] = N_EDGES;
        rowstart[N_NODES] = N_EDGES;
    }
    // zero-lap pad entries so spmm can over-read up to 15 slots past E unmasked
    if (t < 16) ep[N_EDGES + t] = make_int2(0, 0);
}

// ---- pass 1: bin edges by coarse bucket; per-block run reservation -> L2-local scatter ----
__global__ void __launch_bounds__(1024) k_bin(const int* __restrict__ ei,
                                              const float* __restrict__ lap,
                                              int* __restrict__ bcursor,
                                              uint2* __restrict__ ep_tmp) {
    __shared__ int h[N_BUCKETS];
    __shared__ int runbase[N_BUCKETS];
    for (int i = threadIdx.x; i < N_BUCKETS; i += 1024) h[i] = 0;
    __syncthreads();
    int base = blockIdx.x * 16384;
#pragma unroll
    for (int i = 0; i < 16; ++i) {
        int e = base + threadIdx.x + i * 1024;
        if (e < N_EDGES) atomicAdd(&h[ei[e] >> BUCKET_SHIFT], 1);
    }
    __syncthreads();
    for (int i = threadIdx.x; i < N_BUCKETS; i += 1024) {
        int c = h[i];
        runbase[i] = c ? atomicAdd(&bcursor[i], c) : 0;
        h[i] = 0;   // reuse as local cursor
    }
    __syncthreads();
#pragma unroll
    for (int i = 0; i < 16; ++i) {
        int e = base + threadIdx.x + i * 1024;
        if (e < N_EDGES) {
            int row = ei[e], col = ei[N_EDGES + e];
            int b = row >> BUCKET_SHIFT;
            int p = runbase[b] + atomicAdd(&h[b], 1);
            ep_tmp[p] = make_uint2(((unsigned)(row & 127) << 17) | (unsigned)col,
                                   __float_as_uint(lap[e]));
        }
    }
}

// ---- pass 2: per-bucket row sort in LDS; emit rowstart + final ep ----
#define ST_CAP 5120
__global__ void __launch_bounds__(256) k_rsort(const uint2* __restrict__ ep_tmp,
                                               const int* __restrict__ bbase,
                                               int* __restrict__ rowstart,
                                               int2* __restrict__ ep) {
    __shared__ uint2 st[ST_CAP];
    __shared__ int h[128];
    __shared__ int lcur[128];
    int b = blockIdx.x;
    int base = bbase[b], end = bbase[b + 1];
    int n = end - base;
    if (n > ST_CAP) n = ST_CAP;   // statistically unreachable
    for (int i = threadIdx.x; i < n; i += 256) st[i] = ep_tmp[base + i];
    if (threadIdx.x < 128) h[threadIdx.x] = 0;
    __syncthreads();
    for (int i = threadIdx.x; i < n; i += 256) atomicAdd(&h[st[i].x >> 17], 1);
    __syncthreads();
    int t = threadIdx.x;
    int v = (t < 128) ? h[t] : 0;
    for (int off = 1; off < 128; off <<= 1) {
        int tv = (t < 128 && t >= off) ? h[t - off] : 0;
        __syncthreads();
        if (t < 128) h[t] += tv;
        __syncthreads();
    }
    if (t < 128) {
        int ex = h[t] - v;
        int r = (b << BUCKET_SHIFT) + t;
        if (r < N_NODES) rowstart[r] = base + ex;
        lcur[t] = base + ex;
    }
    __syncthreads();
    for (int i = threadIdx.x; i < n; i += 256) {
        uint2 s = st[i];
        int r = s.x >> 17;
        int p = atomicAdd(&lcur[r], 1);
        ep[p] = make_int2((int)(s.x & 0x1FFFFu), (int)s.y);
    }
}

// ---- SpMM gather (fp8 source), pair-edge + 2-deep software pipeline.
// lanes 0-31 process even-slot edges, 32-63 odd-slot; each lane loads 4 B = 4 channels.
// Overhead-stripped v2:
//  * no index clamp: ep has 16 zeroed pad slots past N_EDGES, so batches over-read
//    valid memory; a single (o < elim) cndmask zeroes lap for out-of-row slots.
//  * 32-bit SADDR addressing for both ep (base + voff + imm) and x gathers
//    (col<<7 | lane_base) -- 1 VALU per load instead of 3-7.
//  * pipeline unrolled 2x (A/B role swap) -- no per-batch register rotation.
// zmode: 0 = none, 1 = bf16 z, 3 = fp32 z.
__global__ void __launch_bounds__(256) k_spmm8(
    const unsigned char* __restrict__ xs, const void* __restrict__ z, int zmode,
    unsigned* __restrict__ y8, uint2* __restrict__ yb,
    const int* __restrict__ rowstart, const int2* __restrict__ ep, float a, float b)
{
    int wv = threadIdx.x >> 6, lane = threadIdx.x & 63;
    int r = blockIdx.x * 4 + wv;
    if (r >= N_NODES) return;    // pad rows never stored to out (masked in GEMM)
    int half = lane >> 5, c = lane & 31;
    unsigned vb = (unsigned)c * 4u;
    float acc0 = 0.f, acc1 = 0.f, acc2 = 0.f, acc3 = 0.f;   // channels 4c..4c+3
    int e0 = rowstart[r], e1 = rowstart[r + 1];
    int cnt = e1 - e0;
    if (cnt > 0) {
        int niter = (cnt + 15) >> 4;      // 16 edges per batch
        unsigned eb = (unsigned)(e0 + half) * 8u;   // byte offset of this half's slot 0
        unsigned elim = (unsigned)e1 * 8u;          // row end (bytes)
        const char* epb = (const char*)ep;
        int2 pA[8], pB[8];

#define LOADEP(dst, itv) do {                                            \
        unsigned _eo = eb + (unsigned)(itv) * 128u;                      \
        _Pragma("unroll")                                                \
        for (int _j = 0; _j < 8; ++_j) {                                 \
            unsigned _o = _eo + (unsigned)_j * 16u;                      \
            int2 _p = *(const int2*)(epb + _o);                          \
            _p.y = (_o < elim) ? _p.y : 0;                               \
            dst[_j] = _p;                                                \
        } } while (0)
#define GATHER(gv, src) do {                                             \
        _Pragma("unroll")                                                \
        for (int _j = 0; _j < 8; ++_j)                                   \
            gv[_j] = *(const unsigned*)(xs + ((((unsigned)src[_j].x) << 7) | vb)); \
        } while (0)
#define CONSUME(gv, src) do {                                            \
        _Pragma("unroll")                                                \
        for (int _j = 0; _j < 8; ++_j) {                                 \
            float _l = __int_as_float(src[_j].y);                        \
            f32x2 _flo = __builtin_amdgcn_cvt_pk_f32_fp8((int)gv[_j], false); \
            f32x2 _fhi = __builtin_amdgcn_cvt_pk_f32_fp8((int)gv[_j], true);  \
            acc0 += _l * _flo.x; acc1 += _l * _flo.y;                    \
            acc2 += _l * _fhi.x; acc3 += _l * _fhi.y;                    \
        } } while (0)

        LOADEP(pA, 0);                    // prologue: batch 0
        int it = 0;
        while (it + 2 <= niter) {
            unsigned g0[8], g1[8];
            GATHER(g0, pA);               // issue gathers for batch it
            LOADEP(pB, it + 1);           // issue ep loads for batch it+1 (in flight)
            CONSUME(g0, pA);
            GATHER(g1, pB);               // issue gathers for batch it+1
            if (it + 2 < niter) LOADEP(pA, it + 2);
            CONSUME(g1, pB);
            it += 2;
        }
        if (it < niter) {                 // leftover odd batch, already in pA
            unsigned g0[8];
            GATHER(g0, pA);
            CONSUME(g0, pA);
        }
#undef LOADEP
#undef GATHER
#undef CONSUME
    }
    // butterfly-merge the two halves (lane c <-> lane c+32)
    acc0 += __shfl(acc0, lane ^ 32, 64);
    acc1 += __shfl(acc1, lane ^ 32, 64);
    acc2 += __shfl(acc2, lane ^ 32, 64);
    acc3 += __shfl(acc3, lane ^ 32, 64);
    if (half == 0) {
        float o0 = a * acc0, o1 = a * acc1, o2 = a * acc2, o3 = a * acc3;
        if (zmode == 1) {
            uint2 zg = *((const uint2*)z + (size_t)r * 32 + c);
            o0 += b * bflo(zg.x); o1 += b * bfhi(zg.x);
            o2 += b * bflo(zg.y); o3 += b * bfhi(zg.y);
        } else if (zmode == 3) {
            f32x4 zf = *((const f32x4*)z + (size_t)r * 32 + c);
            o0 += b * zf.x; o1 += b * zf.y; o2 += b * zf.z; o3 += b * zf.w;
        }
        uint2 ob;
        ob.x = (unsigned)f2bf(o0) | ((unsigned)f2bf(o1) << 16);
        ob.y = (unsigned)f2bf(o2) | ((unsigned)f2bf(o3) << 16);
        yb[(size_t)r * 32 + c] = ob;
        if (y8) {
            int pk = __builtin_amdgcn_cvt_pk_fp8_f32(o0, o1, 0, false);
            pk = __builtin_amdgcn_cvt_pk_fp8_f32(o2, o3, pk, true);
            y8[(size_t)r * 32 + c] = (unsigned)pk;
        }
    }
}

// ---- A-fragment loader: fmt 0 = bf16, 1 = fp32 (convert, RNE) ----
__device__ __forceinline__ void load_afrags(const void* A, int fmt, int row, int quad,
                                            bf16x8* frag) {
    if (fmt == 0) {
        const short* p = (const short*)A + (size_t)row * 128 + quad * 8;
#pragma unroll
        for (int kk = 0; kk < 4; ++kk) frag[kk] = *(const bf16x8*)(p + kk * 32);
    } else {
        const float* p = (const float*)A + (size_t)row * 128 + quad * 8;
#pragma unroll
        for (int kk = 0; kk < 4; ++kk) {
            f32x4 u = *(const f32x4*)(p + kk * 32);
            f32x4 v = *(const f32x4*)(p + kk * 32 + 4);
            bf16x8 fr;
            fr[0] = (short)f2bf(u.x); fr[1] = (short)f2bf(u.y);
            fr[2] = (short)f2bf(u.z); fr[3] = (short)f2bf(u.w);
            fr[4] = (short)f2bf(v.x); fr[5] = (short)f2bf(v.y);
            fr[6] = (short)f2bf(v.z); fr[7] = (short)f2bf(v.w);
            frag[kk] = fr;
        }
    }
}

// ---- fused MFMA GEMM pair: out (+)= A0@W0 + A1@W1 (+ bias)   mode 0: write, 1: acc+bias
__global__ void __launch_bounds__(256) k_gemm2(
    const void* __restrict__ A0, int fmt0, const unsigned short* __restrict__ WT0,
    const void* __restrict__ A1, int fmt1, const unsigned short* __restrict__ WT1,
    float* __restrict__ out, const float* __restrict__ bias, int mode)
{
    int wv = threadIdx.x >> 6, lane = threadIdx.x & 63;
    int m = lane & 15, quad = lane >> 4;
    int r0 = blockIdx.x * 64 + wv * 16;
    // fp32 sources are the raw input x [N_NODES,128]: clamp row to stay in-bounds
    int row = r0 + m;
    int row0 = (fmt0 == 1 && row >= N_NODES) ? (N_NODES - 1) : row;
    int row1 = (fmt1 == 1 && row >= N_NODES) ? (N_NODES - 1) : row;
    bf16x8 a0[4], a1[4];
    load_afrags(A0, fmt0, row0, quad, a0);
    load_afrags(A1, fmt1, row1, quad, a1);
#pragma unroll
    for (int ct = 0; ct < 8; ++ct) {
        int c0 = ct * 16;
        const short* Bp0 = (const short*)WT0 + (c0 + m) * 128 + quad * 8;
        const short* Bp1 = (const short*)WT1 + (c0 + m) * 128 + quad * 8;
        f32x4 acc0 = {0.f, 0.f, 0.f, 0.f};
        f32x4 acc1 = {0.f, 0.f, 0.f, 0.f};
#pragma unroll
        for (int kk = 0; kk < 4; ++kk) {
            bf16x8 b0 = *(const bf16x8*)(Bp0 + kk * 32);
            bf16x8 b1 = *(const bf16x8*)(Bp1 + kk * 32);
            acc0 = __builtin_amdgcn_mfma_f32_16x16x32_bf16(a0[kk], b0, acc0, 0, 0, 0);
            acc1 = __builtin_amdgcn_mfma_f32_16x16x32_bf16(a1[kk], b1, acc1, 0, 0, 0);
        }
        int c = c0 + m;                               // C/D layout: col=lane&15, row=quad*4+i
#pragma unroll
        for (int i = 0; i < 4; ++i) {
            int r = r0 + quad * 4 + i;
            if (r < N_NODES) {
                float* o = out + (size_t)r * 128 + c;
                float v = acc0[i] + acc1[i];
                if (mode == 0) *o = v;
                else           *o = *o + v + bias[c];
            }
        }
    }
}

extern "C" void kernel_launch(void* const* d_in, const int* in_sizes, int n_in,
                              void* d_out, int out_size, void* d_ws, size_t ws_size,
                              hipStream_t stream) {
    const float* x    = (const float*)d_in[0];
    const float* lap  = (const float*)d_in[1];
    const float* w    = (const float*)d_in[2];
    const float* bias = (const float*)d_in[3];
    const int*   ei   = (const int*)d_in[4];
    float* out = (float*)d_out;

    char* ws = (char*)d_ws;
    const size_t SZ_BF = (size_t)ROWS_PAD * 128 * 2;   // 25,608,192 B
    const size_t SZ_F8 = (size_t)ROWS_PAD * 128;       // 12,804,096 B
    const size_t SZ_EP = SZ_BF + 256;                  // ep + 16 zero pad slots
    // layout (lifetimes annotated):
    int2* ep            = (int2*)(ws);                              // [0, SZ_EP)
    unsigned char* xf8  = (unsigned char*)(ws + SZ_EP);             // dead after SpMM1
    unsigned char* t1_8 = (unsigned char*)(ws + SZ_EP + SZ_F8);     // dead after SpMM2
    unsigned char* t3_b = (unsigned char*)(ws + SZ_EP);             // reuses xf8+t1_8 region (bf16)
    unsigned char* t1_b = (unsigned char*)(ws + SZ_EP + SZ_BF);
    unsigned char* t2_8 = (unsigned char*)(ws + SZ_EP + 2 * SZ_BF);
    unsigned char* t2_b = (unsigned char*)(ws + SZ_EP + 2 * SZ_BF + SZ_F8);
    uint2* ep_tmp       = (uint2*)(ws + SZ_EP + 2 * SZ_BF);         // aliases t2_8 + t2_b head; dead after rsort
    char* p = ws + SZ_EP + 3 * SZ_BF + SZ_F8;
    int* rowstart = (int*)p; p += 400128;
    int* bcnt     = (int*)p; p += 3200;
    int* bbase    = (int*)p; p += 3200;
    int* bcursor  = (int*)p; p += 3200;
    unsigned short* wt = (unsigned short*)p;           // 4*128*128 bf16

    hipMemsetAsync(bcnt, 0, N_BUCKETS * sizeof(int), stream);
    k_convert_x<<<(ROWS_PAD * 64) / 256, 256, 0, stream>>>(x, (unsigned short*)xf8);
    k_convert_w<<<256, 256, 0, stream>>>(w, wt);
    k_bhist<<<(N_EDGES + 8191) / 8192, 256, 0, stream>>>(ei, bcnt);
    k_bscan<<<1, 1024, 0, stream>>>(bcnt, bbase, bcursor, rowstart, ep);
    k_bin<<<(N_EDGES + 16383) / 16384, 1024, 0, stream>>>(ei, lap, bcursor, ep_tmp);
    k_rsort<<<N_BUCKETS, 256, 0, stream>>>(ep_tmp, bbase, rowstart, ep);

    // Tx1 = L x          (gather fp8 x; write bf16 + fp8)
    k_spmm8<<<ROWS_PAD / 4, 256, 0, stream>>>(xf8, nullptr, 0,
        (unsigned*)t1_8, (uint2*)t1_b, rowstart, ep, 1.f, 0.f);
    // out = x @ W0 + Tx1 @ W1    (x fp32 direct, Tx1 bf16)
    k_gemm2<<<ROWS_PAD / 64, 256, 0, stream>>>(x, 1, wt, t1_b, 0, wt + 16384, out, bias, 0);
    // Tx2 = 2 L Tx1 - x  (gather fp8 Tx1; z fp32 x; write bf16 + fp8)
    k_spmm8<<<ROWS_PAD / 4, 256, 0, stream>>>(t1_8, x, 3,
        (unsigned*)t2_8, (uint2*)t2_b, rowstart, ep, 2.f, -1.f);
    // Tx3 = 2 L Tx2 - Tx1 (gather fp8 Tx2; z bf16 Tx1; write bf16 only, into dead xf8/t1_8 region)
    k_spmm8<<<ROWS_PAD / 4, 256, 0, stream>>>(t2_8, t1_b, 1,
        nullptr, (uint2*)t3_b, rowstart, ep, 2.f, -1.f);
    // out += Tx2 @ W2 + Tx3 @ W3 + bias
    k_gemm2<<<ROWS_PAD / 64, 256, 0, stream>>>(t2_b, 0, wt + 2 * 16384, t3_b, 0, wt + 3 * 16384, out, bias, 1);
}

// Round 2
// 625.570 us; speedup vs baseline: 1.0769x; 1.0769x over previous
//
#include <hip/hip_runtime.h>

#define N_NODES 100000
#define N_EDGES 3200000
#define ROWS_PAD 100032   // multiple of 64 for GEMM tiling
#define N_BUCKETS 782     // ceil(100000/128)
#define BUCKET_SHIFT 7

typedef __attribute__((ext_vector_type(8))) short bf16x8;
typedef __attribute__((ext_vector_type(4))) float f32x4;
typedef __attribute__((ext_vector_type(2))) float f32x2;

__device__ __forceinline__ unsigned short f2bf(float f) {
    unsigned u = __float_as_uint(f);
    unsigned r = (u + 0x7fffu + ((u >> 16) & 1u)) >> 16;  // round-to-nearest-even
    return (unsigned short)r;
}
__device__ __forceinline__ float bflo(unsigned u) { return __uint_as_float(u << 16); }
__device__ __forceinline__ float bfhi(unsigned u) { return __uint_as_float(u & 0xffff0000u); }

// ---- convert x fp32 -> fp8 e4m3 [ROWS_PAD,128], 2 elems/thread, zero pad rows ----
__global__ void k_convert_x(const float* __restrict__ x, unsigned short* __restrict__ xf8) {
    int i = blockIdx.x * 256 + threadIdx.x;          // pair index; grid covers ROWS_PAD*64
    int r = i >> 6;
    float2 f = make_float2(0.f, 0.f);
    if (r < N_NODES) f = *(const float2*)(x + 2 * i);
    int pk = __builtin_amdgcn_cvt_pk_fp8_f32(f.x, f.y, 0, false);
    xf8[i] = (unsigned short)(pk & 0xffff);
}

// ---- convert+transpose W [4][k][c] fp32 -> WT [4][c][k] bf16 ----
__global__ void k_convert_w(const float* __restrict__ w, unsigned short* __restrict__ wt) {
    int i = blockIdx.x * 256 + threadIdx.x;          // 65536 total
    int m = i >> 14, rem = i & 16383, k = rem >> 7, c = rem & 127;
    wt[(m << 14) + (c << 7) + k] = f2bf(w[i]);
}

// ---- coarse bucket histogram (row>>7), LDS-aggregated ----
__global__ void __launch_bounds__(256) k_bhist(const int* __restrict__ ei, int* __restrict__ bcnt) {
    __shared__ int h[N_BUCKETS];
    for (int i = threadIdx.x; i < N_BUCKETS; i += 256) h[i] = 0;
    __syncthreads();
    int base = blockIdx.x * 8192;
#pragma unroll
    for (int i = 0; i < 32; ++i) {
        int e = base + threadIdx.x + i * 256;
        if (e < N_EDGES) atomicAdd(&h[ei[e] >> BUCKET_SHIFT], 1);
    }
    __syncthreads();
    for (int i = threadIdx.x; i < N_BUCKETS; i += 256)
        if (h[i]) atomicAdd(&bcnt[i], h[i]);
}

// ---- one-block exclusive scan of bucket counts; also zero ep's 16 pad slots past E ----
__global__ void __launch_bounds__(1024) k_bscan(const int* __restrict__ bcnt,
                                                int* __restrict__ bbase,
                                                int* __restrict__ bcursor,
                                                int* __restrict__ rowstart,
                                                int2* __restrict__ ep) {
    __shared__ int s[1024];
    int t = threadIdx.x;
    int v = (t < N_BUCKETS) ? bcnt[t] : 0;
    s[t] = v;
    __syncthreads();
    for (int off = 1; off < 1024; off <<= 1) {
        int tv = (t >= off) ? s[t - off] : 0;
        __syncthreads();
        s[t] += tv;
        __syncthreads();
    }
    if (t < N_BUCKETS) {
        int ex = s[t] - v;
        bbase[t] = ex;
        bcursor[t] = ex;
    }
    if (t == 0) {
        bbase[N_BUCKETS] = N_EDGES;
        rowstart[N_NODES] = N_EDGES;
    }
    // zero pad entries so the masked tail batch can over-read valid memory
    if (t < 16) ep[N_EDGES + t] = make_int2(0, 0);
}

// ---- pass 1: bin edges by coarse bucket; per-block run reservation -> L2-local scatter ----
__global__ void __launch_bounds__(1024) k_bin(const int* __restrict__ ei,
                                              const float* __restrict__ lap,
                                              int* __restrict__ bcursor,
                                              uint2* __restrict__ ep_tmp) {
    __shared__ int h[N_BUCKETS];
    __shared__ int runbase[N_BUCKETS];
    for (int i = threadIdx.x; i < N_BUCKETS; i += 1024) h[i] = 0;
    __syncthreads();
    int base = blockIdx.x * 16384;
#pragma unroll
    for (int i = 0; i < 16; ++i) {
        int e = base + threadIdx.x + i * 1024;
        if (e < N_EDGES) atomicAdd(&h[ei[e] >> BUCKET_SHIFT], 1);
    }
    __syncthreads();
    for (int i = threadIdx.x; i < N_BUCKETS; i += 1024) {
        int c = h[i];
        runbase[i] = c ? atomicAdd(&bcursor[i], c) : 0;
        h[i] = 0;   // reuse as local cursor
    }
    __syncthreads();
#pragma unroll
    for (int i = 0; i < 16; ++i) {
        int e = base + threadIdx.x + i * 1024;
        if (e < N_EDGES) {
            int row = ei[e], col = ei[N_EDGES + e];
            int b = row >> BUCKET_SHIFT;
            int p = runbase[b] + atomicAdd(&h[b], 1);
            ep_tmp[p] = make_uint2(((unsigned)(row & 127) << 17) | (unsigned)col,
                                   __float_as_uint(lap[e]));
        }
    }
}

// ---- pass 2: per-bucket row sort in LDS; emit rowstart + final ep ----
#define ST_CAP 5120
__global__ void __launch_bounds__(256) k_rsort(const uint2* __restrict__ ep_tmp,
                                               const int* __restrict__ bbase,
                                               int* __restrict__ rowstart,
                                               int2* __restrict__ ep) {
    __shared__ uint2 st[ST_CAP];
    __shared__ int h[128];
    __shared__ int lcur[128];
    int b = blockIdx.x;
    int base = bbase[b], end = bbase[b + 1];
    int n = end - base;
    if (n > ST_CAP) n = ST_CAP;   // statistically unreachable
    for (int i = threadIdx.x; i < n; i += 256) st[i] = ep_tmp[base + i];
    if (threadIdx.x < 128) h[threadIdx.x] = 0;
    __syncthreads();
    for (int i = threadIdx.x; i < n; i += 256) atomicAdd(&h[st[i].x >> 17], 1);
    __syncthreads();
    int t = threadIdx.x;
    int v = (t < 128) ? h[t] : 0;
    for (int off = 1; off < 128; off <<= 1) {
        int tv = (t < 128 && t >= off) ? h[t - off] : 0;
        __syncthreads();
        if (t < 128) h[t] += tv;
        __syncthreads();
    }
    if (t < 128) {
        int ex = h[t] - v;
        int r = (b << BUCKET_SHIFT) + t;
        if (r < N_NODES) rowstart[r] = base + ex;
        lcur[t] = base + ex;
    }
    __syncthreads();
    for (int i = threadIdx.x; i < n; i += 256) {
        uint2 s = st[i];
        int r = s.x >> 17;
        int p = atomicAdd(&lcur[r], 1);
        ep[p] = make_int2((int)(s.x & 0x1FFFFu), (int)s.y);
    }
}

// ---- SpMM gather (fp8 source), pair-edge + 2-deep software pipeline.
// lanes 0-31 process even-slot edges, 32-63 odd-slot; each lane loads 4 B = 4 channels.
// v3:
//  * full batches ((it+1)*16 <= cnt, wave-uniform test) use an unmasked ep load:
//    zero masking VALU, zero over-read.
//  * only the LAST batch uses the masked load, which cndmasks BOTH col->0 and
//    lap->0: masked gathers all hit row 0 (one hot cache line) -- no scattered
//    waste gathers (round-1 regression: +25% random gather traffic).
//  * 32-bit SADDR addressing for ep (base + voff + imm) and x gathers
//    (col<<7 | lane_base).
//  * pipeline unrolled 2x (A/B role swap) -- no per-batch register rotation.
// zmode: 0 = none, 1 = bf16 z, 3 = fp32 z.
__global__ void __launch_bounds__(256) k_spmm8(
    const unsigned char* __restrict__ xs, const void* __restrict__ z, int zmode,
    unsigned* __restrict__ y8, uint2* __restrict__ yb,
    const int* __restrict__ rowstart, const int2* __restrict__ ep, float a, float b)
{
    int wv = threadIdx.x >> 6, lane = threadIdx.x & 63;
    int r = blockIdx.x * 4 + wv;
    if (r >= N_NODES) return;    // pad rows never stored to out (masked in GEMM)
    int half = lane >> 5, c = lane & 31;
    unsigned vb = (unsigned)c * 4u;
    float acc0 = 0.f, acc1 = 0.f, acc2 = 0.f, acc3 = 0.f;   // channels 4c..4c+3
    int e0 = rowstart[r], e1 = rowstart[r + 1];
    int cnt = e1 - e0;
    if (cnt > 0) {
        int niter = (cnt + 15) >> 4;      // 16 edges per batch
        int nfull = cnt >> 4;             // batches with no out-of-range slot
        unsigned eb = (unsigned)(e0 + half) * 8u;   // byte offset of this half's slot 0
        unsigned elim = (unsigned)e1 * 8u;          // row end (bytes)
        const char* epb = (const char*)ep;
        int2 pA[8], pB[8];

#define LOADEP_F(dst, itv) do {                                          \
        unsigned _eo = eb + (unsigned)(itv) * 128u;                      \
        _Pragma("unroll")                                                \
        for (int _j = 0; _j < 8; ++_j)                                   \
            dst[_j] = *(const int2*)(epb + (_eo + (unsigned)_j * 16u));  \
        } while (0)
#define LOADEP_M(dst, itv) do {                                          \
        unsigned _eo = eb + (unsigned)(itv) * 128u;                      \
        _Pragma("unroll")                                                \
        for (int _j = 0; _j < 8; ++_j) {                                 \
            unsigned _o = _eo + (unsigned)_j * 16u;                      \
            int2 _p = *(const int2*)(epb + _o);                          \
            bool _v = _o < elim;                                         \
            _p.x = _v ? _p.x : 0;     /* masked gathers hit row 0: coalesced */ \
            _p.y = _v ? _p.y : 0;     /* zero lap: no contribution */    \
            dst[_j] = _p;                                                \
        } } while (0)
#define LOADEP(dst, itv) do {                                            \
        if ((itv) < nfull) LOADEP_F(dst, itv);                           \
        else               LOADEP_M(dst, itv);                           \
        } while (0)
#define GATHER(gv, src) do {                                             \
        _Pragma("unroll")                                                \
        for (int _j = 0; _j < 8; ++_j)                                   \
            gv[_j] = *(const unsigned*)(xs + ((((unsigned)src[_j].x) << 7) | vb)); \
        } while (0)
#define CONSUME(gv, src) do {                                            \
        _Pragma("unroll")                                                \
        for (int _j = 0; _j < 8; ++_j) {                                 \
            float _l = __int_as_float(src[_j].y);                        \
            f32x2 _flo = __builtin_amdgcn_cvt_pk_f32_fp8((int)gv[_j], false); \
            f32x2 _fhi = __builtin_amdgcn_cvt_pk_f32_fp8((int)gv[_j], true);  \
            acc0 += _l * _flo.x; acc1 += _l * _flo.y;                    \
            acc2 += _l * _fhi.x; acc3 += _l * _fhi.y;                    \
        } } while (0)

        LOADEP(pA, 0);                    // prologue: batch 0
        int it = 0;
        while (it + 2 <= niter) {
            unsigned g0[8], g1[8];
            GATHER(g0, pA);               // issue gathers for batch it
            LOADEP(pB, it + 1);           // issue ep loads for batch it+1 (in flight)
            CONSUME(g0, pA);
            GATHER(g1, pB);               // issue gathers for batch it+1
            if (it + 2 < niter) LOADEP(pA, it + 2);
            CONSUME(g1, pB);
            it += 2;
        }
        if (it < niter) {                 // leftover odd batch, already in pA
            unsigned g0[8];
            GATHER(g0, pA);
            CONSUME(g0, pA);
        }
#undef LOADEP
#undef LOADEP_F
#undef LOADEP_M
#undef GATHER
#undef CONSUME
    }
    // butterfly-merge the two halves (lane c <-> lane c+32)
    acc0 += __shfl(acc0, lane ^ 32, 64);
    acc1 += __shfl(acc1, lane ^ 32, 64);
    acc2 += __shfl(acc2, lane ^ 32, 64);
    acc3 += __shfl(acc3, lane ^ 32, 64);
    if (half == 0) {
        float o0 = a * acc0, o1 = a * acc1, o2 = a * acc2, o3 = a * acc3;
        if (zmode == 1) {
            uint2 zg = *((const uint2*)z + (size_t)r * 32 + c);
            o0 += b * bflo(zg.x); o1 += b * bfhi(zg.x);
            o2 += b * bflo(zg.y); o3 += b * bfhi(zg.y);
        } else if (zmode == 3) {
            f32x4 zf = *((const f32x4*)z + (size_t)r * 32 + c);
            o0 += b * zf.x; o1 += b * zf.y; o2 += b * zf.z; o3 += b * zf.w;
        }
        uint2 ob;
        ob.x = (unsigned)f2bf(o0) | ((unsigned)f2bf(o1) << 16);
        ob.y = (unsigned)f2bf(o2) | ((unsigned)f2bf(o3) << 16);
        yb[(size_t)r * 32 + c] = ob;
        if (y8) {
            int pk = __builtin_amdgcn_cvt_pk_fp8_f32(o0, o1, 0, false);
            pk = __builtin_amdgcn_cvt_pk_fp8_f32(o2, o3, pk, true);
            y8[(size_t)r * 32 + c] = (unsigned)pk;
        }
    }
}

// ---- A-fragment loader: fmt 0 = bf16, 1 = fp32 (convert, RNE) ----
__device__ __forceinline__ void load_afrags(const void* A, int fmt, int row, int quad,
                                            bf16x8* frag) {
    if (fmt == 0) {
        const short* p = (const short*)A + (size_t)row * 128 + quad * 8;
#pragma unroll
        for (int kk = 0; kk < 4; ++kk) frag[kk] = *(const bf16x8*)(p + kk * 32);
    } else {
        const float* p = (const float*)A + (size_t)row * 128 + quad * 8;
#pragma unroll
        for (int kk = 0; kk < 4; ++kk) {
            f32x4 u = *(const f32x4*)(p + kk * 32);
            f32x4 v = *(const f32x4*)(p + kk * 32 + 4);
            bf16x8 fr;
            fr[0] = (short)f2bf(u.x); fr[1] = (short)f2bf(u.y);
            fr[2] = (short)f2bf(u.z); fr[3] = (short)f2bf(u.w);
            fr[4] = (short)f2bf(v.x); fr[5] = (short)f2bf(v.y);
            fr[6] = (short)f2bf(v.z); fr[7] = (short)f2bf(v.w);
            frag[kk] = fr;
        }
    }
}

// ---- fused MFMA GEMM pair: out (+)= A0@W0 + A1@W1 (+ bias)   mode 0: write, 1: acc+bias
__global__ void __launch_bounds__(256) k_gemm2(
    const void* __restrict__ A0, int fmt0, const unsigned short* __restrict__ WT0,
    const void* __restrict__ A1, int fmt1, const unsigned short* __restrict__ WT1,
    float* __restrict__ out, const float* __restrict__ bias, int mode)
{
    int wv = threadIdx.x >> 6, lane = threadIdx.x & 63;
    int m = lane & 15, quad = lane >> 4;
    int r0 = blockIdx.x * 64 + wv * 16;
    // fp32 sources are the raw input x [N_NODES,128]: clamp row to stay in-bounds
    int row = r0 + m;
    int row0 = (fmt0 == 1 && row >= N_NODES) ? (N_NODES - 1) : row;
    int row1 = (fmt1 == 1 && row >= N_NODES) ? (N_NODES - 1) : row;
    bf16x8 a0[4], a1[4];
    load_afrags(A0, fmt0, row0, quad, a0);
    load_afrags(A1, fmt1, row1, quad, a1);
#pragma unroll
    for (int ct = 0; ct < 8; ++ct) {
        int c0 = ct * 16;
        const short* Bp0 = (const short*)WT0 + (c0 + m) * 128 + quad * 8;
        const short* Bp1 = (const short*)WT1 + (c0 + m) * 128 + quad * 8;
        f32x4 acc0 = {0.f, 0.f, 0.f, 0.f};
        f32x4 acc1 = {0.f, 0.f, 0.f, 0.f};
#pragma unroll
        for (int kk = 0; kk < 4; ++kk) {
            bf16x8 b0 = *(const bf16x8*)(Bp0 + kk * 32);
            bf16x8 b1 = *(const bf16x8*)(Bp1 + kk * 32);
            acc0 = __builtin_amdgcn_mfma_f32_16x16x32_bf16(a0[kk], b0, acc0, 0, 0, 0);
            acc1 = __builtin_amdgcn_mfma_f32_16x16x32_bf16(a1[kk], b1, acc1, 0, 0, 0);
        }
        int c = c0 + m;                               // C/D layout: col=lane&15, row=quad*4+i
#pragma unroll
        for (int i = 0; i < 4; ++i) {
            int r = r0 + quad * 4 + i;
            if (r < N_NODES) {
                float* o = out + (size_t)r * 128 + c;
                float v = acc0[i] + acc1[i];
                if (mode == 0) *o = v;
                else           *o = *o + v + bias[c];
            }
        }
    }
}

extern "C" void kernel_launch(void* const* d_in, const int* in_sizes, int n_in,
                              void* d_out, int out_size, void* d_ws, size_t ws_size,
                              hipStream_t stream) {
    const float* x    = (const float*)d_in[0];
    const float* lap  = (const float*)d_in[1];
    const float* w    = (const float*)d_in[2];
    const float* bias = (const float*)d_in[3];
    const int*   ei   = (const int*)d_in[4];
    float* out = (float*)d_out;

    char* ws = (char*)d_ws;
    const size_t SZ_BF = (size_t)ROWS_PAD * 128 * 2;   // 25,608,192 B
    const size_t SZ_F8 = (size_t)ROWS_PAD * 128;       // 12,804,096 B
    const size_t SZ_EP = SZ_BF + 256;                  // ep + 16 zero pad slots
    // layout (lifetimes annotated):
    int2* ep            = (int2*)(ws);                              // [0, SZ_EP)
    unsigned char* xf8  = (unsigned char*)(ws + SZ_EP);             // dead after SpMM1
    unsigned char* t1_8 = (unsigned char*)(ws + SZ_EP + SZ_F8);     // dead after SpMM2
    unsigned char* t3_b = (unsigned char*)(ws + SZ_EP);             // reuses xf8+t1_8 region (bf16)
    unsigned char* t1_b = (unsigned char*)(ws + SZ_EP + SZ_BF);
    unsigned char* t2_8 = (unsigned char*)(ws + SZ_EP + 2 * SZ_BF);
    unsigned char* t2_b = (unsigned char*)(ws + SZ_EP + 2 * SZ_BF + SZ_F8);
    uint2* ep_tmp       = (uint2*)(ws + SZ_EP + 2 * SZ_BF);         // aliases t2_8 + t2_b head; dead after rsort
    char* p = ws + SZ_EP + 3 * SZ_BF + SZ_F8;
    int* rowstart = (int*)p; p += 400128;
    int* bcnt     = (int*)p; p += 3200;
    int* bbase    = (int*)p; p += 3200;
    int* bcursor  = (int*)p; p += 3200;
    unsigned short* wt = (unsigned short*)p;           // 4*128*128 bf16

    hipMemsetAsync(bcnt, 0, N_BUCKETS * sizeof(int), stream);
    k_convert_x<<<(ROWS_PAD * 64) / 256, 256, 0, stream>>>(x, (unsigned short*)xf8);
    k_convert_w<<<256, 256, 0, stream>>>(w, wt);
    k_bhist<<<(N_EDGES + 8191) / 8192, 256, 0, stream>>>(ei, bcnt);
    k_bscan<<<1, 1024, 0, stream>>>(bcnt, bbase, bcursor, rowstart, ep);
    k_bin<<<(N_EDGES + 16383) / 16384, 1024, 0, stream>>>(ei, lap, bcursor, ep_tmp);
    k_rsort<<<N_BUCKETS, 256, 0, stream>>>(ep_tmp, bbase, rowstart, ep);

    // Tx1 = L x          (gather fp8 x; write bf16 + fp8)
    k_spmm8<<<ROWS_PAD / 4, 256, 0, stream>>>(xf8, nullptr, 0,
        (unsigned*)t1_8, (uint2*)t1_b, rowstart, ep, 1.f, 0.f);
    // out = x @ W0 + Tx1 @ W1    (x fp32 direct, Tx1 bf16)
    k_gemm2<<<ROWS_PAD / 64, 256, 0, stream>>>(x, 1, wt, t1_b, 0, wt + 16384, out, bias, 0);
    // Tx2 = 2 L Tx1 - x  (gather fp8 Tx1; z fp32 x; write bf16 + fp8)
    k_spmm8<<<ROWS_PAD / 4, 256, 0, stream>>>(t1_8, x, 3,
        (unsigned*)t2_8, (uint2*)t2_b, rowstart, ep, 2.f, -1.f);
    // Tx3 = 2 L Tx2 - Tx1 (gather fp8 Tx2; z bf16 Tx1; write bf16 only, into dead xf8/t1_8 region)
    k_spmm8<<<ROWS_PAD / 4, 256, 0, stream>>>(t2_8, t1_b, 1,
        nullptr, (uint2*)t3_b, rowstart, ep, 2.f, -1.f);
    // out += Tx2 @ W2 + Tx3 @ W3 + bias
    k_gemm2<<<ROWS_PAD / 64, 256, 0, stream>>>(t2_b, 0, wt + 2 * 16384, t3_b, 0, wt + 3 * 16384, out, bias, 1);
}